// Round 16
// baseline (20.966 us; speedup 1.0000x reference)
//
#include <hip/hip_runtime.h>
#include <hip/hip_bf16.h>

// Problem dims (fixed): n=128, d=256, ic=16, oc=16, r=10
// x:   [n, d, ic, r]  f32; w: [d, ic, oc, r] f32; out: [n, d, oc, r] f32
// out[n,d,oc,r] = log( sum_ic exp(x)*exp(w) ) - log( sum_ic exp(w) )
//
// v16: DRAM-granularity attack. Every prior variant fixed d per block ->
// 640B contiguous runs at 160KB stride -> ~2.6 TB/s effective (vs 6.5 for
// contiguous fill). Block = (16 n, 4 d): per-n reads/writes span 2560B
// contiguous. prep (v15-verified) bakes exp(w) B-fragments + lcs into d_ws.
// Main: wave = d; B-frags + lcs in regs; es = 16 slots only (kg>=2 lanes
// use zero regs = exact K-pad, v13/14-verified); ONE barrier; direct stores.

typedef __attribute__((ext_vector_type(8))) short bf16x8;
typedef __attribute__((ext_vector_type(4))) float f32x4;

#define LCS_OFF 1310720   // bytes: wfrag = 256 d * 10 r * 512 B

__device__ __forceinline__ unsigned short f2bf(float v) {
    unsigned u = __float_as_uint(v);
    u += 0x7FFF + ((u >> 16) & 1);
    return (unsigned short)(u >> 16);
}

// ---------------- prep: wfrag[(d*10+r)*128 + lane*4 + wsel] + lcs -----------
// (verbatim from v15 — correctness-verified there)
__global__ __launch_bounds__(256) void prep_kernel(const float* __restrict__ w,
                                                   void* __restrict__ ws) {
    __shared__ float lexp[2560];         // [(ic*16+oc)*10 + r]
    const int d   = blockIdx.x;
    const int tid = threadIdx.x;         // = ic*16 + oc
    const int ic  = tid >> 4, oc = tid & 15;

    const float* wp = w + d * 2560 + ic * 160 + oc * 10;
#pragma unroll
    for (int k = 0; k < 5; ++k) {
        float2 v = *reinterpret_cast<const float2*>(wp + 2 * k);
        lexp[tid * 10 + 2 * k]     = __expf(v.x);
        lexp[tid * 10 + 2 * k + 1] = __expf(v.y);
    }
    __syncthreads();

    if (tid < 160) {
        const int o2 = tid / 10, rr = tid - (tid / 10) * 10;
        float s = 0.f;
#pragma unroll
        for (int i2 = 0; i2 < 16; ++i2) s += lexp[(i2 * 16 + o2) * 10 + rr];
        float* lcs = reinterpret_cast<float*>(reinterpret_cast<char*>(ws) + LCS_OFF);
        lcs[d * 160 + tid] = __logf(s);
    }

    unsigned* wf = reinterpret_cast<unsigned*>(ws);
    const int idx    = tid & 127;
    const int lane32 = idx >> 2;
    const int wsel   = idx & 3;
    const int kg     = lane32 >> 4;
    const int oc2    = lane32 & 15;
    const int s0     = kg * 8 + wsel * 2;
#pragma unroll
    for (int rr2 = 0; rr2 < 5; ++rr2) {
        const int r = rr2 * 2 + (tid >> 7);
        const unsigned lo = f2bf(lexp[(s0 * 16 + oc2) * 10 + r]);
        const unsigned hi = f2bf(lexp[((s0 + 1) * 16 + oc2) * 10 + r]);
        wf[(d * 10 + r) * 128 + idx] = lo | (hi << 16);
    }
}

// ---------------- main: 512 blocks x 256 thr, block = (16 n, 4 d) -----------
#define ESROW 168   // shorts per (d_l, n_l) row: 160 data + 8 pad

__global__ __launch_bounds__(256, 3) void main_kernel(const float* __restrict__ x,
                                                      const void* __restrict__ ws,
                                                      float* __restrict__ out) {
    __shared__ __align__(16) unsigned short es[64 * ESROW];  // 21 KB

    const int tid  = threadIdx.x;
    const int dc   = blockIdx.x & 63;    // d-chunk (4 d each)
    const int ncx  = blockIdx.x >> 6;    // n-chunk 0..7
    const int wid  = tid >> 6;           // wave = d_local 0..3
    const int lane = tid & 63;
    const int lm   = lane & 15;          // oc / A-row
    const int kg   = lane >> 4;          // k-group 0..3
    const int d0   = dc * 4;
    const int d_g  = d0 + wid;
    const int n_b  = ncx * 16;

    // ---- B-fragments + lcs straight to registers (L2/L3-hot) ---------------
    bf16x8 bfr[10];
    const unsigned* wf = reinterpret_cast<const unsigned*>(ws);
#pragma unroll
    for (int r = 0; r < 10; ++r) {
        if (lane < 32)
            bfr[r] = *reinterpret_cast<const bf16x8*>(&wf[(d_g * 10 + r) * 128 + lane * 4]);
        else
            bfr[r] = bf16x8{0, 0, 0, 0, 0, 0, 0, 0};   // K-pad slots 16..31
    }
    float lc[10];
    {
        const float* lcs = reinterpret_cast<const float*>(
            reinterpret_cast<const char*>(ws) + LCS_OFF) + d_g * 160 + lm * 10;
#pragma unroll
        for (int k = 0; k < 5; ++k) {
            float2 v = *reinterpret_cast<const float2*>(lcs + 2 * k);
            lc[2 * k] = v.x; lc[2 * k + 1] = v.y;
        }
    }

    // ---- stage exp(x): thread = (n_l, d_l2, seg); 2560B contiguous per n ---
    {
        const int n_l  = tid >> 4;       // 0..15
        const int part = tid & 15;       // 16 threads cover one 2560B n-span
        const int d_l2 = part >> 2;      // 0..3
        const int seg  = part & 3;       // 0..3 -> ic 4seg..4seg+3, all r
        const float* xg = x + ((n_b + n_l) * 256 + d0 + d_l2) * 160 + seg * 40;
        float4 xv[10];
#pragma unroll
        for (int k = 0; k < 10; ++k) xv[k] = *reinterpret_cast<const float4*>(xg + 4 * k);
        const float* xf = reinterpret_cast<const float*>(xv);
        unsigned short* erow = &es[(d_l2 * 16 + n_l) * ESROW];
#pragma unroll
        for (int r = 0; r < 10; ++r) {
            const unsigned lo = (unsigned)f2bf(__expf(xf[r]))      | ((unsigned)f2bf(__expf(xf[10 + r])) << 16);
            const unsigned hi = (unsigned)f2bf(__expf(xf[20 + r])) | ((unsigned)f2bf(__expf(xf[30 + r])) << 16);
            *reinterpret_cast<uint2*>(&erow[r * 16 + seg * 4]) = make_uint2(lo, hi);
        }
    }
    __syncthreads();

    // ---- MFMA: A from LDS (kg<2 only; kg>=2 = zero regs), B from regs ------
    const unsigned short* arow = &es[(wid * 16 + lm) * ESROW + kg * 8];
    const bf16x8 zero8 = {0, 0, 0, 0, 0, 0, 0, 0};
    const f32x4 zeroc = {0.f, 0.f, 0.f, 0.f};
    f32x4 acc[10];
#pragma unroll
    for (int r = 0; r < 10; ++r) {
        bf16x8 a = (kg < 2) ? *reinterpret_cast<const bf16x8*>(&arow[r * 16]) : zero8;
        acc[r] = __builtin_amdgcn_mfma_f32_16x16x32_bf16(a, bfr[r], zeroc, 0, 0, 0);
    }

    // ---- epilogue: C col=lm(oc), row=kg*4+j (m89-verified); direct stores --
#pragma unroll
    for (int j = 0; j < 4; ++j) {
        const int n = n_b + kg * 4 + j;
        float* og = out + (n * 256 + d_g) * 160 + lm * 10;
#pragma unroll
        for (int h = 0; h < 5; ++h) {
            float2 o;
            o.x = __logf(acc[2 * h][j])     - lc[2 * h];
            o.y = __logf(acc[2 * h + 1][j]) - lc[2 * h + 1];
            *reinterpret_cast<float2*>(og + 2 * h) = o;
        }
    }
}

extern "C" void kernel_launch(void* const* d_in, const int* in_sizes, int n_in,
                              void* d_out, int out_size, void* d_ws, size_t ws_size,
                              hipStream_t stream) {
    const float* x = (const float*)d_in[0];
    const float* w = (const float*)d_in[1];
    float* out = (float*)d_out;

    prep_kernel<<<256, 256, 0, stream>>>(w, d_ws);
    // 512 blocks: dc = bid&63 (4-d chunk), ncx = bid>>6 (16-n chunk)
    main_kernel<<<512, 256, 0, stream>>>(x, d_ws, out);
}